// Round 3
// baseline (450.106 us; speedup 1.0000x reference)
//
#include <hip/hip_runtime.h>
#include <math.h>

#define N 8192
#define IN_F 256
#define OUT_F 128
#define ALPHA 0.2f

typedef _Float16 f16;
typedef __attribute__((ext_vector_type(4))) float f32x4;
typedef __attribute__((ext_vector_type(8))) _Float16 f16x8;
typedef __attribute__((ext_vector_type(4))) _Float16 f16x4;

// ---------------- Kernel 0: WT[f][k] = (f16) W[k][f] ----------------
__global__ __launch_bounds__(256) void k_prep(const float* __restrict__ W,
                                              f16* __restrict__ WT) {
    int idx = blockIdx.x * 256 + threadIdx.x;
    int f = idx >> 8;
    int k = idx & 255;
    WT[idx] = (f16)W[k * OUT_F + f];
}

// ---------------- Kernel 1: Wh = h@W via MFMA; emit tiled WhT(f16), src, dst ----
// WhT_t layout: [64 tiles][128 f][128 j_local]  (tile ct covers nodes ct*128..+128)
#define HS 280   // f16 row stride: 560 B = 140 dw === 12 (mod 32), conflict-optimal b128
__global__ __launch_bounds__(256) void k_wh(const float* __restrict__ h,
                                            const f16* __restrict__ WT,   // [128][256]
                                            const float* __restrict__ a,
                                            f16* __restrict__ WhT,        // tiled
                                            float* __restrict__ src,
                                            float* __restrict__ dst) {
    __shared__ __align__(16) f16 hA[32][HS];
    __shared__ __align__(16) f16 outT[128][40];    // [col][row-in-block]
    __shared__ float sred[4][32], dred[4][32];

    const int t = threadIdx.x;
    const int i0 = blockIdx.x * 32;
    const int wv = t >> 6, l = t & 63, ln = l & 15, lq = l >> 4;

    {
        const float4* hg = (const float4*)(h + (size_t)i0 * IN_F);
#pragma unroll
        for (int it = 0; it < 8; ++it) {
            int idx = t + it * 256;
            int r = idx >> 6;
            int c4 = (idx & 63) * 4;
            float4 v = hg[idx];
            f16x4 p = { (f16)v.x, (f16)v.y, (f16)v.z, (f16)v.w };
            *(f16x4*)&hA[r][c4] = p;
        }
    }
    __syncthreads();

    f32x4 acc00 = {0.f,0.f,0.f,0.f}, acc01 = {0.f,0.f,0.f,0.f};
    f32x4 acc10 = {0.f,0.f,0.f,0.f}, acc11 = {0.f,0.f,0.f,0.f};
    const int f0 = 32 * wv;

#pragma unroll
    for (int ks = 0; ks < 8; ++ks) {
        const int k0 = 32 * ks + 8 * lq;
        f16x8 a0 = *(const f16x8*)&hA[ln][k0];
        f16x8 a1 = *(const f16x8*)&hA[16 + ln][k0];
        f16x8 b0 = *(const f16x8*)(WT + (size_t)(f0 + ln) * IN_F + k0);
        f16x8 b1 = *(const f16x8*)(WT + (size_t)(f0 + 16 + ln) * IN_F + k0);
        acc00 = __builtin_amdgcn_mfma_f32_16x16x32_f16(a0, b0, acc00, 0, 0, 0);
        acc01 = __builtin_amdgcn_mfma_f32_16x16x32_f16(a0, b1, acc01, 0, 0, 0);
        acc10 = __builtin_amdgcn_mfma_f32_16x16x32_f16(a1, b0, acc10, 0, 0, 0);
        acc11 = __builtin_amdgcn_mfma_f32_16x16x32_f16(a1, b1, acc11, 0, 0, 0);
    }

    const float a1c0 = a[f0 + ln],      a2c0 = a[128 + f0 + ln];
    const float a1c1 = a[f0 + 16 + ln], a2c1 = a[128 + f0 + 16 + ln];
    float sp[8], dp[8];
#pragma unroll
    for (int i = 0; i < 8; ++i) { sp[i] = 0.f; dp[i] = 0.f; }

#pragma unroll
    for (int hh = 0; hh < 2; ++hh) {
        f32x4 v0 = hh ? acc10 : acc00;
        f32x4 v1 = hh ? acc11 : acc01;
        f16x4 p0, p1;
#pragma unroll
        for (int rg = 0; rg < 4; ++rg) {
            sp[hh * 4 + rg] += v0[rg] * a1c0 + v1[rg] * a1c1;
            dp[hh * 4 + rg] += v0[rg] * a2c0 + v1[rg] * a2c1;
            p0[rg] = (f16)v0[rg];
            p1[rg] = (f16)v1[rg];
        }
        *(f16x4*)&outT[f0 + ln][16 * hh + 4 * lq] = p0;
        *(f16x4*)&outT[f0 + 16 + ln][16 * hh + 4 * lq] = p1;
    }
#pragma unroll
    for (int i = 0; i < 8; ++i) {
        float s = sp[i], d = dp[i];
        s += __shfl_down(s, 8, 16); d += __shfl_down(d, 8, 16);
        s += __shfl_down(s, 4, 16); d += __shfl_down(d, 4, 16);
        s += __shfl_down(s, 2, 16); d += __shfl_down(d, 2, 16);
        s += __shfl_down(s, 1, 16); d += __shfl_down(d, 1, 16);
        if (ln == 0) {
            int row = 16 * (i >> 2) + 4 * lq + (i & 3);
            sred[wv][row] = s;
            dred[wv][row] = d;
        }
    }
    __syncthreads();
    if (t < 32) {
        src[i0 + t] = sred[0][t] + sred[1][t] + sred[2][t] + sred[3][t];
        dst[i0 + t] = dred[0][t] + dred[1][t] + dred[2][t] + dred[3][t];
    }
    // write tiled WhT: tile ct = i0/128, local offset jo = i0 % 128
    {
        const int col = t & 127, g = t >> 7;
        const int ct = i0 >> 7, jo = i0 & 127;
        f16x8 q0 = *(const f16x8*)&outT[col][16 * g];
        f16x8 q1 = *(const f16x8*)&outT[col][16 * g + 8];
        f16* dstp = WhT + (size_t)ct * (128 * 128) + (size_t)col * 128 + jo + 16 * g;
        *(f16x8*)(dstp) = q0;
        *(f16x8*)(dstp + 8) = q1;
    }
}

// ---------------- Kernel 2: fused masked-softmax attention partials ----------------
// grid (512, 2): x = 16-row group, y = j-half. Block 256 threads (4 waves).
// Producer thread: row pr=t>>4, j-octet pm=t&15. Consumer wave wv: f in [32wv,32wv+32).
#define TI 16
#define NJ 128
#define JS 2
#define NCL (N / NJ / JS)   // 32 chunks per block
#define WSTRIDE 152         // f16; 304 B = 76 dw === 12 (mod 32), conflict-optimal b128
__global__ __launch_bounds__(256, 4) void k_attn(const int* __restrict__ adj,
                                                 const f16* __restrict__ WhT,  // tiled
                                                 const float* __restrict__ src,
                                                 const float* __restrict__ dst,
                                                 float* __restrict__ p_part,
                                                 float* __restrict__ l_part) {
    __shared__ __align__(16) f16 wA[2][TI][WSTRIDE];   // 9728 B
    __shared__ float lfin[TI];

    const int t = threadIdx.x;
    const int i0 = blockIdx.x * TI;
    const int jh = blockIdx.y;
    const int pr = t >> 4;          // 0..15
    const int pm = t & 15;
    const int wv = t >> 6;          // 0..3
    const int l = t & 63, ln = l & 15, lq = l >> 4;

    const float my_src = src[i0 + pr];
    const float cshift = fabsf(my_src) + 4.0f;
    float lp = 0.f;
    f32x4 accv0 = {0.f,0.f,0.f,0.f}, accv1 = {0.f,0.f,0.f,0.f};

    const int* arow = adj + (size_t)(i0 + pr) * N + jh * (N / JS) + 8 * pm;
    const float* drow = dst + jh * (N / JS) + 8 * pm;
    // B base: tile gc = jh*NCL + c; within tile: f-row (32wv+ln), j_local = 32ks+8lq
    const f16* Bb = WhT + (size_t)(jh * NCL) * (128 * 128)
                  + (size_t)(32 * wv + ln) * 128 + 8 * lq;

    int4 aA0, aB0, aA1, aB1;
    float4 dA0, dB0, dA1, dB1;

    auto issue = [&](int c, int4& xA, int4& xB, float4& xdA, float4& xdB) {
        const int j0 = c * NJ;
        xA = *(const int4*)(arow + j0);
        xB = *(const int4*)(arow + j0 + 4);
        xdA = *(const float4*)(drow + j0);
        xdB = *(const float4*)(drow + j0 + 4);
    };
    auto produce = [&](int c, const int4& xA, const int4& xB,
                       const float4& xdA, const float4& xdB) {
        float w[8];
        const int*   av = (const int*)&xA;
        const int*   bv = (const int*)&xB;
        const float* df = (const float*)&xdA;
        const float* ef = (const float*)&xdB;
#pragma unroll
        for (int k = 0; k < 4; ++k) {
            float e = my_src + df[k];
            float lk = e > 0.f ? e : ALPHA * e;
            w[k] = av[k] ? __expf(lk - cshift) : 0.f;
        }
#pragma unroll
        for (int k = 0; k < 4; ++k) {
            float e = my_src + ef[k];
            float lk = e > 0.f ? e : ALPHA * e;
            w[4 + k] = bv[k] ? __expf(lk - cshift) : 0.f;
        }
        f16x8 wp;
#pragma unroll
        for (int k = 0; k < 8; ++k) { lp += w[k]; wp[k] = (f16)w[k]; }
        *(f16x8*)&wA[c & 1][pr][8 * pm] = wp;
    };
    auto mpass = [&](int c) {
        const f16* wb = &wA[c & 1][0][0];
        const f16* bp = Bb + (size_t)c * (128 * 128);
#pragma unroll
        for (int ks = 0; ks < 4; ++ks) {
            const int k0 = 32 * ks;
            f16x8 a0 = *(const f16x8*)(wb + ln * WSTRIDE + k0 + 8 * lq);
            f16x8 b0 = *(const f16x8*)(bp + k0);
            f16x8 b1 = *(const f16x8*)(bp + 16 * 128 + k0);
            accv0 = __builtin_amdgcn_mfma_f32_16x16x32_f16(a0, b0, accv0, 0, 0, 0);
            accv1 = __builtin_amdgcn_mfma_f32_16x16x32_f16(a0, b1, accv1, 0, 0, 0);
        }
    };

    issue(0, aA0, aB0, dA0, dB0);
    produce(0, aA0, aB0, dA0, dB0);
    issue(1, aA1, aB1, dA1, dB1);
    __syncthreads();

    for (int cc = 0; cc < NCL; cc += 2) {
        if (cc + 2 < NCL) issue(cc + 2, aA0, aB0, dA0, dB0);
        mpass(cc);
        produce(cc + 1, aA1, aB1, dA1, dB1);
        __syncthreads();
        if (cc + 3 < NCL) issue(cc + 3, aA1, aB1, dA1, dB1);
        mpass(cc + 1);
        if (cc + 2 < NCL) produce(cc + 2, aA0, aB0, dA0, dB0);
        __syncthreads();
    }

    // partial softmax denominator for this j-half
    {
        float v = lp;
        v += __shfl_down(v, 8, 16);
        v += __shfl_down(v, 4, 16);
        v += __shfl_down(v, 2, 16);
        v += __shfl_down(v, 1, 16);
        if (pm == 0) lfin[pr] = v;
    }
    __syncthreads();
    if (t < TI) l_part[(size_t)jh * N + i0 + t] = lfin[t];

    // partial accumulator: C layout col=ln (f), row=4lq+rg
    float* pb = p_part + (size_t)jh * N * OUT_F;
#pragma unroll
    for (int hh = 0; hh < 2; ++hh) {
        f32x4 av = hh ? accv1 : accv0;
#pragma unroll
        for (int rg = 0; rg < 4; ++rg) {
            const int row = 4 * lq + rg;
            pb[(size_t)(i0 + row) * OUT_F + 32 * wv + 16 * hh + ln] = av[rg];
        }
    }
}

// ---------------- Kernel 3: combine j-half partials, normalize, ELU ----------------
__global__ __launch_bounds__(256) void k_comb(const float* __restrict__ p_part,
                                              const float* __restrict__ l_part,
                                              float* __restrict__ out) {
    const int idx = blockIdx.x * 256 + threadIdx.x;   // N*OUT_F total
    const int row = idx >> 7;
    float p = p_part[idx] + p_part[(size_t)N * OUT_F + idx];
    float lsum = l_part[row] + l_part[N + row];
    float hp = p / lsum;
    out[idx] = hp > 0.f ? hp : expm1f(hp);
}

extern "C" void kernel_launch(void* const* d_in, const int* in_sizes, int n_in,
                              void* d_out, int out_size, void* d_ws, size_t ws_size,
                              hipStream_t stream) {
    const float* h   = (const float*)d_in[0];
    const int*   adj = (const int*)d_in[1];
    const float* W   = (const float*)d_in[2];
    const float* a   = (const float*)d_in[3];
    float* out = (float*)d_out;

    char* ws = (char*)d_ws;
    f16*   WT     = (f16*)ws;                       ws += 64 * 1024;          // 64 KB
    f16*   WhT    = (f16*)ws;                       ws += 2 * 1024 * 1024;    // 2 MB tiled
    float* src    = (float*)ws;                     ws += N * sizeof(float);
    float* dst    = (float*)ws;                     ws += N * sizeof(float);
    float* l_part = (float*)ws;                     ws += JS * N * sizeof(float);
    float* p_part = (float*)ws;                     // JS * N * OUT_F * 4 = 8 MB

    k_prep<<<128, 256, 0, stream>>>(W, WT);
    k_wh<<<N / 32, 256, 0, stream>>>(h, WT, a, WhT, src, dst);
    dim3 agrid(N / TI, JS);
    k_attn<<<agrid, 256, 0, stream>>>(adj, WhT, src, dst, p_part, l_part);
    k_comb<<<N * OUT_F / 256, 256, 0, stream>>>(p_part, l_part, out);
}

// Round 4
// 443.382 us; speedup vs baseline: 1.0152x; 1.0152x over previous
//
#include <hip/hip_runtime.h>
#include <math.h>

#define N 8192
#define IN_F 256
#define OUT_F 128
#define ALPHA 0.2f
#define JS 8                 // j-range split
#define NSTEP 32             // 32-j steps per wave: (N/JS)/32

typedef _Float16 f16;
typedef __attribute__((ext_vector_type(4))) float f32x4;
typedef __attribute__((ext_vector_type(8))) _Float16 f16x8;
typedef __attribute__((ext_vector_type(4))) _Float16 f16x4;

// ---------------- Kernel 0: WT[f][k] = (f16) W[k][f] ----------------
__global__ __launch_bounds__(256) void k_prep(const float* __restrict__ W,
                                              f16* __restrict__ WT) {
    int idx = blockIdx.x * 256 + threadIdx.x;
    int f = idx >> 8;
    int k = idx & 255;
    WT[idx] = (f16)W[k * OUT_F + f];
}

// ---------------- Kernel 1: Wh = h@W via MFMA; emit tiled WhT(f16), src, dst ----
// WhT layout: [64 tiles][128 f][128 j_local]
#define HS 280
__global__ __launch_bounds__(256) void k_wh(const float* __restrict__ h,
                                            const f16* __restrict__ WT,
                                            const float* __restrict__ a,
                                            f16* __restrict__ WhT,
                                            float* __restrict__ src,
                                            float* __restrict__ dst) {
    __shared__ __align__(16) f16 hA[32][HS];
    __shared__ __align__(16) f16 outT[128][40];
    __shared__ float sred[4][32], dred[4][32];

    const int t = threadIdx.x;
    const int i0 = blockIdx.x * 32;
    const int wv = t >> 6, l = t & 63, ln = l & 15, lq = l >> 4;

    {
        const float4* hg = (const float4*)(h + (size_t)i0 * IN_F);
#pragma unroll
        for (int it = 0; it < 8; ++it) {
            int idx = t + it * 256;
            int r = idx >> 6;
            int c4 = (idx & 63) * 4;
            float4 v = hg[idx];
            f16x4 p = { (f16)v.x, (f16)v.y, (f16)v.z, (f16)v.w };
            *(f16x4*)&hA[r][c4] = p;
        }
    }
    __syncthreads();

    f32x4 acc00 = {0.f,0.f,0.f,0.f}, acc01 = {0.f,0.f,0.f,0.f};
    f32x4 acc10 = {0.f,0.f,0.f,0.f}, acc11 = {0.f,0.f,0.f,0.f};
    const int f0 = 32 * wv;

#pragma unroll
    for (int ks = 0; ks < 8; ++ks) {
        const int k0 = 32 * ks + 8 * lq;
        f16x8 a0 = *(const f16x8*)&hA[ln][k0];
        f16x8 a1 = *(const f16x8*)&hA[16 + ln][k0];
        f16x8 b0 = *(const f16x8*)(WT + (size_t)(f0 + ln) * IN_F + k0);
        f16x8 b1 = *(const f16x8*)(WT + (size_t)(f0 + 16 + ln) * IN_F + k0);
        acc00 = __builtin_amdgcn_mfma_f32_16x16x32_f16(a0, b0, acc00, 0, 0, 0);
        acc01 = __builtin_amdgcn_mfma_f32_16x16x32_f16(a0, b1, acc01, 0, 0, 0);
        acc10 = __builtin_amdgcn_mfma_f32_16x16x32_f16(a1, b0, acc10, 0, 0, 0);
        acc11 = __builtin_amdgcn_mfma_f32_16x16x32_f16(a1, b1, acc11, 0, 0, 0);
    }

    const float a1c0 = a[f0 + ln],      a2c0 = a[128 + f0 + ln];
    const float a1c1 = a[f0 + 16 + ln], a2c1 = a[128 + f0 + 16 + ln];
    float sp[8], dp[8];
#pragma unroll
    for (int i = 0; i < 8; ++i) { sp[i] = 0.f; dp[i] = 0.f; }

#pragma unroll
    for (int hh = 0; hh < 2; ++hh) {
        f32x4 v0 = hh ? acc10 : acc00;
        f32x4 v1 = hh ? acc11 : acc01;
        f16x4 p0, p1;
#pragma unroll
        for (int rg = 0; rg < 4; ++rg) {
            sp[hh * 4 + rg] += v0[rg] * a1c0 + v1[rg] * a1c1;
            dp[hh * 4 + rg] += v0[rg] * a2c0 + v1[rg] * a2c1;
            p0[rg] = (f16)v0[rg];
            p1[rg] = (f16)v1[rg];
        }
        *(f16x4*)&outT[f0 + ln][16 * hh + 4 * lq] = p0;
        *(f16x4*)&outT[f0 + 16 + ln][16 * hh + 4 * lq] = p1;
    }
#pragma unroll
    for (int i = 0; i < 8; ++i) {
        float s = sp[i], d = dp[i];
        s += __shfl_down(s, 8, 16); d += __shfl_down(d, 8, 16);
        s += __shfl_down(s, 4, 16); d += __shfl_down(d, 4, 16);
        s += __shfl_down(s, 2, 16); d += __shfl_down(d, 2, 16);
        s += __shfl_down(s, 1, 16); d += __shfl_down(d, 1, 16);
        if (ln == 0) {
            int row = 16 * (i >> 2) + 4 * lq + (i & 3);
            sred[wv][row] = s;
            dred[wv][row] = d;
        }
    }
    __syncthreads();
    if (t < 32) {
        src[i0 + t] = sred[0][t] + sred[1][t] + sred[2][t] + sred[3][t];
        dst[i0 + t] = dred[0][t] + dred[1][t] + dred[2][t] + dred[3][t];
    }
    {
        const int col = t & 127, g = t >> 7;
        const int ct = i0 >> 7, jo = i0 & 127;
        f16x8 q0 = *(const f16x8*)&outT[col][16 * g];
        f16x8 q1 = *(const f16x8*)&outT[col][16 * g + 8];
        f16* dstp = WhT + (size_t)ct * (128 * 128) + (size_t)col * 128 + jo + 16 * g;
        *(f16x8*)(dstp) = q0;
        *(f16x8*)(dstp + 8) = q1;
    }
}

// ---------------- Kernel 2: barrier-free fused attention partials ----------------
// One wave owns 32 rows x 1024 j. Thread (ln,lq) computes exp-weights for rows
// i0+ln / i0+16+ln at j-octet 8*lq of each 32-j step -- exactly its MFMA
// A-fragment. No LDS, no __syncthreads in the hot loop; depth-2 register
// prefetch keeps adj streaming from HBM continuously.
__global__ __launch_bounds__(256, 2) void k_attn(const int* __restrict__ adj,
                                                 const f16* __restrict__ WhT,
                                                 const float* __restrict__ src,
                                                 const float* __restrict__ dst,
                                                 float* __restrict__ p_part,
                                                 float* __restrict__ l_part) {
    const int t = threadIdx.x;
    const int wv = t >> 6, l = t & 63, ln = l & 15, lq = l >> 4;
    const int i0 = (blockIdx.x * 4 + wv) * 32;        // wave's first row
    const int jq = blockIdx.y;
    const int jbase = jq * (N / JS);                  // 1024 j per wave

    const float src0 = src[i0 + ln];
    const float src1 = src[i0 + 16 + ln];
    const float c0 = fabsf(src0) + 4.0f;
    const float c1 = fabsf(src1) + 4.0f;
    float lp0 = 0.f, lp1 = 0.f;

    f32x4 acc0[8], acc1[8];
#pragma unroll
    for (int ft = 0; ft < 8; ++ft) {
        acc0[ft] = (f32x4){0.f,0.f,0.f,0.f};
        acc1[ft] = (f32x4){0.f,0.f,0.f,0.f};
    }

    const int* arow0 = adj + (size_t)(i0 + ln) * N + jbase + 8 * lq;
    const int* arow1 = arow0 + (size_t)16 * N;
    const float* drow = dst + jbase + 8 * lq;
    const f16* Bb = WhT + (size_t)(jq * 8) * (128 * 128) + (size_t)ln * 128 + 8 * lq;

    // depth-2 rolling prefetch registers (parity-indexed)
    int4 pa0[2][2], pa1[2][2];
    float4 pd[2][2];

    auto issue = [&](int s, int p) {
        const int off = 32 * (s & (NSTEP - 1));   // clamp keeps tail loads in-bounds
        pa0[p][0] = *(const int4*)(arow0 + off);
        pa0[p][1] = *(const int4*)(arow0 + off + 4);
        pa1[p][0] = *(const int4*)(arow1 + off);
        pa1[p][1] = *(const int4*)(arow1 + off + 4);
        pd[p][0]  = *(const float4*)(drow + off);
        pd[p][1]  = *(const float4*)(drow + off + 4);
    };

    issue(0, 0);
    issue(1, 1);

#pragma unroll 4
    for (int s = 0; s < NSTEP; ++s) {
        const int p = s & 1;
        const int4 a00 = pa0[p][0], a01 = pa0[p][1];
        const int4 a10 = pa1[p][0], a11 = pa1[p][1];
        const float4 d0 = pd[p][0], d1 = pd[p][1];
        issue(s + 2, p);

        const int* av0 = (const int*)&a00;     // rows set 0, j 0..3 then 4..7
        const int* av1 = (const int*)&a01;
        const int* bv0 = (const int*)&a10;     // rows set 1
        const int* bv1 = (const int*)&a11;
        const float* df0 = (const float*)&d0;
        const float* df1 = (const float*)&d1;

        f16x8 af0, af1;
#pragma unroll
        for (int k = 0; k < 4; ++k) {
            float e0 = src0 + df0[k];
            float w0 = av0[k] ? __expf(fmaxf(e0, ALPHA * e0) - c0) : 0.f;
            lp0 += w0; af0[k] = (f16)w0;
            float e1 = src1 + df0[k];
            float w1 = bv0[k] ? __expf(fmaxf(e1, ALPHA * e1) - c1) : 0.f;
            lp1 += w1; af1[k] = (f16)w1;
        }
#pragma unroll
        for (int k = 0; k < 4; ++k) {
            float e0 = src0 + df1[k];
            float w0 = av1[k] ? __expf(fmaxf(e0, ALPHA * e0) - c0) : 0.f;
            lp0 += w0; af0[4 + k] = (f16)w0;
            float e1 = src1 + df1[k];
            float w1 = bv1[k] ? __expf(fmaxf(e1, ALPHA * e1) - c1) : 0.f;
            lp1 += w1; af1[4 + k] = (f16)w1;
        }

        const f16* bp = Bb + (s >> 2) * (128 * 128) + (s & 3) * 32;
#pragma unroll
        for (int ft = 0; ft < 8; ++ft) {
            f16x8 bf = *(const f16x8*)(bp + ft * (16 * 128));
            acc0[ft] = __builtin_amdgcn_mfma_f32_16x16x32_f16(af0, bf, acc0[ft], 0, 0, 0);
            acc1[ft] = __builtin_amdgcn_mfma_f32_16x16x32_f16(af1, bf, acc1[ft], 0, 0, 0);
        }
    }

    // reduce lp over the 4 lq-lanes of each row (lanes ln, ln+16, ln+32, ln+48)
    lp0 += __shfl_down(lp0, 32); lp0 += __shfl_down(lp0, 16);
    lp1 += __shfl_down(lp1, 32); lp1 += __shfl_down(lp1, 16);
    if (l < 16) {
        l_part[(size_t)jq * N + i0 + l] = lp0;
        l_part[(size_t)jq * N + i0 + 16 + l] = lp1;
    }

    // store partial accumulators (C layout: col=ln, row=4*lq+rg)
    float* pb = p_part + (size_t)jq * N * OUT_F;
#pragma unroll
    for (int ft = 0; ft < 8; ++ft) {
#pragma unroll
        for (int rg = 0; rg < 4; ++rg) {
            pb[(size_t)(i0 + 4 * lq + rg) * OUT_F + 16 * ft + ln] = acc0[ft][rg];
            pb[(size_t)(i0 + 16 + 4 * lq + rg) * OUT_F + 16 * ft + ln] = acc1[ft][rg];
        }
    }
}

// ---------------- Kernel 3: combine j-eighth partials, normalize, ELU ----------------
__global__ __launch_bounds__(256) void k_comb(const float* __restrict__ p_part,
                                              const float* __restrict__ l_part,
                                              float* __restrict__ out) {
    const int idx4 = blockIdx.x * 256 + threadIdx.x;   // float4 index, N*OUT_F/4 total
    const int row = idx4 >> 5;                          // 32 float4 per row
    const float4* pp = (const float4*)p_part;
    float4 p = pp[idx4];
    float lsum = l_part[row];
#pragma unroll
    for (int q = 1; q < JS; ++q) {
        float4 v = pp[(size_t)q * (N * OUT_F / 4) + idx4];
        p.x += v.x; p.y += v.y; p.z += v.z; p.w += v.w;
        lsum += l_part[(size_t)q * N + row];
    }
    float inv = 1.0f / lsum;
    float4 r;
    r.x = p.x * inv; r.x = r.x > 0.f ? r.x : expm1f(r.x);
    r.y = p.y * inv; r.y = r.y > 0.f ? r.y : expm1f(r.y);
    r.z = p.z * inv; r.z = r.z > 0.f ? r.z : expm1f(r.z);
    r.w = p.w * inv; r.w = r.w > 0.f ? r.w : expm1f(r.w);
    ((float4*)out)[idx4] = r;
}

extern "C" void kernel_launch(void* const* d_in, const int* in_sizes, int n_in,
                              void* d_out, int out_size, void* d_ws, size_t ws_size,
                              hipStream_t stream) {
    const float* h   = (const float*)d_in[0];
    const int*   adj = (const int*)d_in[1];
    const float* W   = (const float*)d_in[2];
    const float* a   = (const float*)d_in[3];
    float* out = (float*)d_out;

    char* ws = (char*)d_ws;
    f16*   WT     = (f16*)ws;                       ws += 64 * 1024;
    f16*   WhT    = (f16*)ws;                       ws += 2 * 1024 * 1024;
    float* src    = (float*)ws;                     ws += N * sizeof(float);
    float* dst    = (float*)ws;                     ws += N * sizeof(float);
    float* l_part = (float*)ws;                     ws += (size_t)JS * N * sizeof(float);
    float* p_part = (float*)ws;                     // JS * N * OUT_F * 4 = 32 MB

    k_prep<<<128, 256, 0, stream>>>(W, WT);
    k_wh<<<N / 32, 256, 0, stream>>>(h, WT, a, WhT, src, dst);
    dim3 agrid(N / 128, JS);                        // (64, 8), 4 waves/block
    k_attn<<<agrid, 256, 0, stream>>>(adj, WhT, src, dst, p_part, l_part);
    k_comb<<<N * OUT_F / 4 / 256, 256, 0, stream>>>(p_part, l_part, out);
}